// Round 8
// baseline (516.439 us; speedup 1.0000x reference)
//
#include <hip/hip_runtime.h>

// Stable stream compaction: y[:count] = x[x>0] in original order, y[count:n]=0,
// y[out_size-1] = (float)count.
//
// 3 kernels, reduce-then-scan (single-pass lookback abandoned: R1=1956us,
// R4=995us, R5=1575us vs ~180us here — cross-XCD atomic latency).
//
// R8 structure — slot staging to halve the L3 working set:
//   k_stage : read x ONCE with NONTEMPORAL loads (x is dead after this pass;
//             don't let it occupy L3), compact each chunk's positives into a
//             per-block slot in ws with NORMAL stores (~128 MB of touched
//             lines -> comfortably L3-resident; x was 256 MB = exactly L3
//             capacity, which is why R3/R7's re-read mostly missed).
//   k_scan  : single-block exclusive scan of block sums (+ total at [nb],
//             + (float)count to y[out_size-1]).
//   k_emit  : read slots (L3 hits), shift by pad=excl&3 via LDS, aligned
//             nt float4 stores to y, fused nt zerofill of [count, n).
// Serialized HBM traffic ~641 MB (256R + 128W + 257W) vs 769 before.

#define BLOCK 256
#define VPT 16               // elems per thread (contiguous)
#define CHUNK (BLOCK * VPT)  // 4096
#define SCAN_THREADS 1024
#define SCAN_VPT 16          // scan supports up to 16384 block sums

typedef float floatx4 __attribute__((ext_vector_type(4)));

// exclusive block scan over 256 threads (4 waves); returns exclusive rank,
// sets *blockTotal. lds must have >= 9 ints.
__device__ __forceinline__ int block_scan_excl_256(int val, int* lds, int* blockTotal) {
    const int tid  = threadIdx.x;
    const int lane = tid & 63;
    const int wave = tid >> 6;
    int incl = val;
#pragma unroll
    for (int off = 1; off < 64; off <<= 1) {
        const int y = __shfl_up(incl, off, 64);
        if (lane >= off) incl += y;
    }
    if (lane == 63) lds[wave] = incl;
    __syncthreads();
    if (tid == 0) {
        const int s0 = lds[0], s1 = lds[1], s2 = lds[2], s3 = lds[3];
        lds[4] = 0; lds[5] = s0; lds[6] = s0 + s1; lds[7] = s0 + s1 + s2;
        lds[8] = s0 + s1 + s2 + s3;
    }
    __syncthreads();
    const int ex = lds[4 + wave] + incl - val;
    *blockTotal = lds[8];
    return ex;
}

// Pass 1: count + compact positives into per-block ws slot (slot b = CHUNK
// floats at slots[b*CHUNK]; only first cnt_b are meaningful, tail garbage ok).
__global__ void __launch_bounds__(BLOCK)
k_stage(const float* __restrict__ x, int n, float* __restrict__ slots,
        int* __restrict__ blockSums) {
    __shared__ __align__(16) float vals[CHUNK];
    __shared__ int scan_lds[9];
    const int tid = threadIdx.x;
    const long long chunkBase = (long long)blockIdx.x * CHUNK;
    const long long tbase = chunkBase + tid * VPT;

    float v[VPT];
    if (chunkBase + CHUNK <= n) {
#pragma unroll
        for (int k = 0; k < 4; ++k) {
            const floatx4 f = __builtin_nontemporal_load(
                reinterpret_cast<const floatx4*>(x + tbase + 4 * k));
            v[4 * k + 0] = f.x; v[4 * k + 1] = f.y; v[4 * k + 2] = f.z; v[4 * k + 3] = f.w;
        }
    } else {
#pragma unroll
        for (int j = 0; j < VPT; ++j)
            v[j] = (tbase + j < n) ? x[tbase + j] : 0.f;
    }

    int c = 0;
#pragma unroll
    for (int j = 0; j < VPT; ++j) c += (v[j] > 0.f);

    int total;
    int r = block_scan_excl_256(c, scan_lds, &total);
    if (tid == 0) blockSums[blockIdx.x] = total;

#pragma unroll
    for (int j = 0; j < VPT; ++j) {
        if (v[j] > 0.f) vals[r++] = v[j];
    }
    __syncthreads();

    // NORMAL (L3-allocating) aligned float4 stores; tail quad garbage is fine.
    float* slot = slots + chunkBase;
    const int nq = (total + 3) >> 2;
    for (int t = tid; t < nq; t += BLOCK) {
        *reinterpret_cast<floatx4*>(slot + 4 * t) =
            *reinterpret_cast<const floatx4*>(&vals[4 * t]);
    }
}

// Single-block exclusive scan of blockSums (numBlocks <= SCAN_THREADS*SCAN_VPT).
// Writes exclusive prefixes in place, total at sums[numBlocks], count to y tail.
__global__ void k_scan(int* __restrict__ sums, int numBlocks,
                       float* __restrict__ countOutF) {
    __shared__ int lds[32];
    const int tid  = threadIdx.x;
    const int lane = tid & 63;
    const int wave = tid >> 6;   // 16 waves

    int vals[SCAN_VPT];
    const int base = tid * SCAN_VPT;
    int local = 0;
#pragma unroll
    for (int j = 0; j < SCAN_VPT; ++j) {
        const int i = base + j;
        const int v = (i < numBlocks) ? sums[i] : 0;
        vals[j] = local;         // thread-local exclusive
        local += v;
    }
    int incl = local;
#pragma unroll
    for (int off = 1; off < 64; off <<= 1) {
        const int y = __shfl_up(incl, off, 64);
        if (lane >= off) incl += y;
    }
    if (lane == 63) lds[wave] = incl;
    __syncthreads();
    if (wave == 0 && lane < 16) {
        int w = lds[lane];
#pragma unroll
        for (int off = 1; off < 16; off <<= 1) {
            const int y = __shfl_up(w, off, 16);
            if ((lane & 15) >= off) w += y;
        }
        lds[16 + lane] = w;      // inclusive wave prefix
    }
    __syncthreads();
    const int waveEx   = (wave == 0) ? 0 : lds[16 + wave - 1];
    const int threadEx = waveEx + incl - local;
#pragma unroll
    for (int j = 0; j < SCAN_VPT; ++j) {
        const int i = base + j;
        if (i < numBlocks) sums[i] = threadEx + vals[j];
    }
    if (tid == SCAN_THREADS - 1) {
        const int total = waveEx + incl;
        sums[numBlocks] = total;
        *countOutF = (float)total;
    }
}

// Pass 3: slots -> y (shifted by pad via LDS, aligned nt stores) + nt zerofill.
__global__ void __launch_bounds__(BLOCK)
k_emit(const float* __restrict__ slots, int n,
       const int* __restrict__ offs, float* __restrict__ y) {
    __shared__ __align__(16) float vals[CHUNK + 4];
    const int tid = threadIdx.x;
    const int b = blockIdx.x;
    const long long chunkBase = (long long)b * CHUNK;

    const int excl = offs[b];
    const int cnt  = offs[b + 1] - excl;
    const int pad  = excl & 3;

    // Slot -> LDS at [pad + k]. nt loads: hit L3 if resident, don't re-allocate.
    const float* slot = slots + chunkBase;
    const int nqs = (cnt + 3) >> 2;
    for (int t = tid; t < nqs; t += BLOCK) {
        const floatx4 f = __builtin_nontemporal_load(
            reinterpret_cast<const floatx4*>(slot + 4 * t));
        const int k = pad + 4 * t;
        vals[k] = f.x; vals[k + 1] = f.y; vals[k + 2] = f.z; vals[k + 3] = f.w;
    }
    __syncthreads();

    // Aligned nontemporal float4 stores: vals[k] <-> y[yb + k], yb = excl - pad.
    const int m = pad + cnt;
    const long long yb = (long long)excl - pad;
    const int nq = (m + 3) >> 2;
    for (int t = tid; t < nq; t += BLOCK) {
        const int k0 = 4 * t;
        if (k0 >= pad && k0 + 4 <= m) {
            __builtin_nontemporal_store(
                *reinterpret_cast<const floatx4*>(&vals[k0]),
                reinterpret_cast<floatx4*>(y + yb + k0));
        } else {
            const int ks = (k0 < pad) ? pad : k0;
            const int ke = (k0 + 4 < m) ? k0 + 4 : m;
            for (int k = ks; k < ke; ++k)
                __builtin_nontemporal_store(vals[k], y + yb + k);
        }
    }

    // Fused zerofill (nontemporal): this block's zeros tile a slice of
    // [count, n) from the top down; regions are disjoint and cover it exactly.
    const int rem   = (int)(n - chunkBase);
    const int elems = rem < CHUNK ? rem : CHUNK;
    const int z     = elems - cnt;
    const long long zhi = (long long)n - (chunkBase - excl);
    const long long zlo = zhi - z;
    const long long za  = (zlo + 3) & ~3LL;    // first aligned quad start
    const long long zb  = zhi & ~3LL;          // last aligned quad end
    if (za >= zb) {
        for (long long j = zlo + tid; j < zhi; j += BLOCK)
            __builtin_nontemporal_store(0.f, y + j);
    } else {
        if (tid < (int)(za - zlo))
            __builtin_nontemporal_store(0.f, y + zlo + tid);               // head (<=3)
        if (tid >= 4 && tid - 4 < (int)(zhi - zb))
            __builtin_nontemporal_store(0.f, y + zb + tid - 4);            // tail (<=3)
        const int zq = (int)((zb - za) >> 2);
        const floatx4 zero = (floatx4)(0.f);
        for (int t = tid; t < zq; t += BLOCK) {
            __builtin_nontemporal_store(zero, reinterpret_cast<floatx4*>(y + za + 4 * t));
        }
    }
}

extern "C" void kernel_launch(void* const* d_in, const int* in_sizes, int n_in,
                              void* d_out, int out_size, void* d_ws, size_t ws_size,
                              hipStream_t stream) {
    const float* x = (const float*)d_in[0];
    float* y = (float*)d_out;
    const int n = in_sizes[0];

    const int numBlocks = (n + CHUNK - 1) / CHUNK;   // 16384 for N=64M
    float* slots = (float*)d_ws;                     // numBlocks*CHUNK floats (256 MB span)
    int* blockSums = (int*)(slots + (long long)numBlocks * CHUNK);  // numBlocks+1 ints

    k_stage<<<numBlocks, BLOCK, 0, stream>>>(x, n, slots, blockSums);
    k_scan<<<1, SCAN_THREADS, 0, stream>>>(blockSums, numBlocks, y + (out_size - 1));
    k_emit<<<numBlocks, BLOCK, 0, stream>>>(slots, n, blockSums, y);
}

// Round 9
// 489.040 us; speedup vs baseline: 1.0560x; 1.0560x over previous
//
#include <hip/hip_runtime.h>

// Stable stream compaction: y[:count] = x[x>0] in original order, y[count:n]=0,
// y[out_size-1] = (float)count.
//
// reduce-then-scan, 3 kernels. Single-pass lookback abandoned (R1=1956us PRE
// chain, R4=995us flat AGG, R5=1575us hierarchical spin hotspot vs ~180us
// here — cross-XCD atomic visibility latency). Slot staging abandoned
// (R8=516us: staged lines don't survive L3 against the y stream).
//
// R9 = R7 + fractional L3 residency:
//   k_count   : reads x; FIRST QUARTER (64 MB) with NONTEMPORAL loads (no
//               LLC allocate), rest (192 MB) normal. Leaves a clean 192 MB
//               of x resident — comfortably under the 256 MB capacity cliff
//               that limited R7's reuse (x = exactly L3 size).
//   k_scan    : single-block exclusive scan of 16384 block sums + count out.
//   k_scatter : REVERSE chunk order (starts at resident tail), ALL y stores
//               NONTEMPORAL (don't evict x), LDS-staged pad-aligned float4
//               stores, fused nt zerofill.

#define BLOCK 256
#define VPT 16               // elems per thread (contiguous, scatter only)
#define CHUNK (BLOCK * VPT)  // 4096
#define SCAN_THREADS 1024
#define SCAN_VPT 16          // scan supports up to 16384 block sums

typedef float floatx4 __attribute__((ext_vector_type(4)));

__global__ void __launch_bounds__(BLOCK)
k_count(const float* __restrict__ x, int n, int ntCut, int* __restrict__ blockSums) {
    const int tid = threadIdx.x;
    const long long chunkBase = (long long)blockIdx.x * CHUNK;
    int cnt = 0;
    if (chunkBase + CHUNK <= n) {
        const float* p = x + chunkBase + tid * 4;
        if ((int)blockIdx.x < ntCut) {
            // nt loads: stream, do not allocate in LLC (this quarter is
            // sacrificed; keeps the resident set comfortably under capacity)
#pragma unroll
            for (int it = 0; it < 4; ++it) {
                const floatx4 v = __builtin_nontemporal_load(
                    reinterpret_cast<const floatx4*>(p + it * (BLOCK * 4)));
                cnt += (v.x > 0.f) + (v.y > 0.f) + (v.z > 0.f) + (v.w > 0.f);
            }
        } else {
#pragma unroll
            for (int it = 0; it < 4; ++it) {
                const float4 v = *reinterpret_cast<const float4*>(p + it * (BLOCK * 4));
                cnt += (v.x > 0.f) + (v.y > 0.f) + (v.z > 0.f) + (v.w > 0.f);
            }
        }
    } else {
        const long long lim = (chunkBase + CHUNK < n) ? chunkBase + CHUNK : n;
        for (long long j = chunkBase + tid; j < lim; j += BLOCK) cnt += (x[j] > 0.f);
    }
#pragma unroll
    for (int off = 32; off > 0; off >>= 1) cnt += __shfl_down(cnt, off, 64);
    __shared__ int lds[4];
    if ((tid & 63) == 0) lds[tid >> 6] = cnt;
    __syncthreads();
    if (tid == 0) blockSums[blockIdx.x] = lds[0] + lds[1] + lds[2] + lds[3];
}

// Single-block exclusive scan of blockSums (numBlocks <= SCAN_THREADS*SCAN_VPT).
__global__ void k_scan(int* __restrict__ sums, int numBlocks,
                       int* __restrict__ countOut, float* __restrict__ countOutF) {
    __shared__ int lds[32];
    const int tid  = threadIdx.x;
    const int lane = tid & 63;
    const int wave = tid >> 6;   // 16 waves

    int vals[SCAN_VPT];
    const int base = tid * SCAN_VPT;
    int local = 0;
#pragma unroll
    for (int j = 0; j < SCAN_VPT; ++j) {
        const int i = base + j;
        const int v = (i < numBlocks) ? sums[i] : 0;
        vals[j] = local;         // thread-local exclusive
        local += v;
    }
    int incl = local;
#pragma unroll
    for (int off = 1; off < 64; off <<= 1) {
        const int y = __shfl_up(incl, off, 64);
        if (lane >= off) incl += y;
    }
    if (lane == 63) lds[wave] = incl;
    __syncthreads();
    if (wave == 0 && lane < 16) {
        int w = lds[lane];
#pragma unroll
        for (int off = 1; off < 16; off <<= 1) {
            const int y = __shfl_up(w, off, 16);
            if ((lane & 15) >= off) w += y;
        }
        lds[16 + lane] = w;      // inclusive wave prefix
    }
    __syncthreads();
    const int waveEx   = (wave == 0) ? 0 : lds[16 + wave - 1];
    const int threadEx = waveEx + incl - local;
#pragma unroll
    for (int j = 0; j < SCAN_VPT; ++j) {
        const int i = base + j;
        if (i < numBlocks) sums[i] = threadEx + vals[j];
    }
    if (tid == SCAN_THREADS - 1) {
        const int total = waveEx + incl;
        *countOut  = total;
        *countOutF = (float)total;
    }
}

// exclusive block scan over 256 threads (4 waves); returns exclusive rank,
// sets *blockTotal. lds must have >= 9 ints.
__device__ __forceinline__ int block_scan_excl_256(int val, int* lds, int* blockTotal) {
    const int tid  = threadIdx.x;
    const int lane = tid & 63;
    const int wave = tid >> 6;
    int incl = val;
#pragma unroll
    for (int off = 1; off < 64; off <<= 1) {
        const int y = __shfl_up(incl, off, 64);
        if (lane >= off) incl += y;
    }
    if (lane == 63) lds[wave] = incl;
    __syncthreads();
    if (tid == 0) {
        const int s0 = lds[0], s1 = lds[1], s2 = lds[2], s3 = lds[3];
        lds[4] = 0; lds[5] = s0; lds[6] = s0 + s1; lds[7] = s0 + s1 + s2;
        lds[8] = s0 + s1 + s2 + s3;
    }
    __syncthreads();
    const int ex = lds[4 + wave] + incl - val;
    *blockTotal = lds[8];
    return ex;
}

__global__ void __launch_bounds__(BLOCK)
k_scatter(const float* __restrict__ x, int n, int numBlocks,
          const int* __restrict__ blockOffsets, float* __restrict__ y) {
    __shared__ __align__(16) float vals[CHUNK + 4];  // +pad (up to 3) for aligned output
    __shared__ int scan_lds[9];
    const int tid = threadIdx.x;
    const int chunk = numBlocks - 1 - blockIdx.x;    // reverse order for L3 reuse
    const int chunkBase = chunk * CHUNK;
    const long long tbase = (long long)chunkBase + tid * VPT;

    float v[VPT];
    if ((long long)chunkBase + CHUNK <= n) {
#pragma unroll
        for (int k = 0; k < 4; ++k) {
            const float4 f = *reinterpret_cast<const float4*>(x + tbase + 4 * k);
            v[4 * k + 0] = f.x; v[4 * k + 1] = f.y; v[4 * k + 2] = f.z; v[4 * k + 3] = f.w;
        }
    } else {
#pragma unroll
        for (int j = 0; j < VPT; ++j)
            v[j] = (tbase + j < n) ? x[tbase + j] : 0.f;
    }

    int c = 0;
#pragma unroll
    for (int j = 0; j < VPT; ++j) c += (v[j] > 0.f);

    int total;
    int r = block_scan_excl_256(c, scan_lds, &total);

    const int excl = blockOffsets[chunk];
    const int pad  = excl & 3;                 // stage shifted so output is 16B-aligned

    r += pad;
#pragma unroll
    for (int j = 0; j < VPT; ++j) {
        if (v[j] > 0.f) vals[r++] = v[j];
    }
    __syncthreads();

    // Vectorized NONTEMPORAL store of positives: vals[k] <-> y[yb + k],
    // yb = excl - pad (mod 4 == 0). nt: don't allocate y lines in LLC.
    const int m = pad + total;
    const long long yb = (long long)excl - pad;
    const int nq = (m + 3) >> 2;
    for (int t = tid; t < nq; t += BLOCK) {
        const int k0 = 4 * t;
        if (k0 >= pad && k0 + 4 <= m) {
            __builtin_nontemporal_store(
                *reinterpret_cast<const floatx4*>(&vals[k0]),
                reinterpret_cast<floatx4*>(y + yb + k0));
        } else {
            const int ks = (k0 < pad) ? pad : k0;
            const int ke = (k0 + 4 < m) ? k0 + 4 : m;
            for (int k = ks; k < ke; ++k)
                __builtin_nontemporal_store(vals[k], y + yb + k);
        }
    }

    // Fused zerofill (nontemporal): this block's zeros tile a slice of
    // [count, n) from the top down; regions are disjoint and cover it exactly.
    const int rem   = n - chunkBase;
    const int elems = rem < CHUNK ? rem : CHUNK;
    const int z     = elems - total;
    const long long zhi = (long long)n - (chunkBase - excl);
    const long long zlo = zhi - z;
    const long long za  = (zlo + 3) & ~3LL;    // first aligned quad start
    const long long zb  = zhi & ~3LL;          // last aligned quad end
    if (za >= zb) {
        for (long long j = zlo + tid; j < zhi; j += BLOCK)
            __builtin_nontemporal_store(0.f, y + j);
    } else {
        if (tid < (int)(za - zlo))
            __builtin_nontemporal_store(0.f, y + zlo + tid);               // head (<=3)
        if (tid >= 4 && tid - 4 < (int)(zhi - zb))
            __builtin_nontemporal_store(0.f, y + zb + tid - 4);            // tail (<=3)
        const int zq = (int)((zb - za) >> 2);
        const floatx4 zero = (floatx4)(0.f);
        for (int t = tid; t < zq; t += BLOCK) {
            __builtin_nontemporal_store(zero, reinterpret_cast<floatx4*>(y + za + 4 * t));
        }
    }
}

extern "C" void kernel_launch(void* const* d_in, const int* in_sizes, int n_in,
                              void* d_out, int out_size, void* d_ws, size_t ws_size,
                              hipStream_t stream) {
    const float* x = (const float*)d_in[0];
    float* y = (float*)d_out;
    const int n = in_sizes[0];

    int* blockSums = (int*)d_ws;
    const int numBlocks = (n + CHUNK - 1) / CHUNK;   // 16384 for N=64M
    int* countPtr = blockSums + numBlocks;
    const int ntCut = numBlocks >> 2;                // first quarter: nt loads

    k_count<<<numBlocks, BLOCK, 0, stream>>>(x, n, ntCut, blockSums);
    k_scan<<<1, SCAN_THREADS, 0, stream>>>(blockSums, numBlocks,
                                           countPtr, y + (out_size - 1));
    k_scatter<<<numBlocks, BLOCK, 0, stream>>>(x, n, numBlocks, blockSums, y);
}